// Round 1
// baseline (302.732 us; speedup 1.0000x reference)
//
#include <hip/hip_runtime.h>
#include <hip/hip_bf16.h>

// PeakBinner: out[b, g*50+o] = relu( sum_k x[b, g*250+k] * W[g,o,k] )
// Round 6: occupancy push. Same BM=32 tile / 33.3 KB LDS / one barrier, but
// 512-thread blocks (8 waves = 2 m-tiles x 4 n-groups, one 16x16 acc each)
// -> 4 blocks x 8 waves = 32 waves/CU (100% of cap) to hide the staging-HBM
// and K-loop-L2 latency chains that dominated at 16 waves/CU.
// __launch_bounds__(512,8) caps VGPR at 64 (est. ~50, no spill).

constexpr int INPUT  = 10000;
constexpr int GROUPS = 39;
constexpr int GS     = 500;
constexpr int STEP   = 250;
constexpr int OPG    = 50;
constexpr int OUTW   = 1950;
constexpr int KP     = 512;          // padded K
constexpr int BM     = 32;
constexpr int LDA    = KP + 8;       // shorts; 1040-B row stride (4 banks mod 32)

__device__ __hip_bfloat16 Wb[GROUPS * OPG * KP];   // 2.0 MB, L2-resident

typedef __attribute__((ext_vector_type(8))) short  short8;
typedef __attribute__((ext_vector_type(4))) float  float4v;

__device__ __forceinline__ unsigned bf2pack(float a, float b) {
    union { float f; unsigned u; } x, y; x.f = a; y.f = b;
    unsigned lo = (x.u + 0x7fffu + ((x.u >> 16) & 1u)) >> 16;
    unsigned hi = (y.u + 0x7fffu + ((y.u >> 16) & 1u)) & 0xffff0000u;
    return hi | lo;
}

__global__ void prep_w(const float* __restrict__ W) {
    const int slot = blockIdx.x * 256 + threadIdx.x;     // dword slots
    if (slot >= GROUPS * OPG * (KP / 2)) return;
    const int go = slot / (KP / 2);
    const int k  = (slot - go * (KP / 2)) * 2;
    float2 v = {0.f, 0.f};
    if (k < GS) v = *(const float2*)(W + (size_t)go * GS + k);
    ((unsigned*)Wb)[slot] = bf2pack(v.x, v.y);
}

__global__ __launch_bounds__(512, 8)
void peak_binner_kernel(const float* __restrict__ x,
                        float* __restrict__ out, int batch)
{
    __shared__ __align__(16) short As[BM * LDA];   // 33,280 B -> 4 blocks/CU

    const int g     = blockIdx.x;
    const int m0    = blockIdx.y * BM;
    const int tid   = threadIdx.x;
    const int lane  = tid & 63;
    const int wave  = tid >> 6;
    const int nwave = wave & 3;          // n-group 0..3
    const int mwave = wave >> 2;         // m-tile 0..1
    const int fm    = lane & 15;
    const int l4    = lane >> 4;
    const int nb    = (nwave == 3) ? 34 : nwave * 16;   // wave n-rows nb..nb+15

    // ---- stage A: 32 rows x 500 fp32 -> bf16, cols 500..511 zeroed ----
    // 512 threads cover 2 rows/step (256 threads x float2 each); 16 steps,
    // batched 8-deep for MLP. Wave = one contiguous 512-B slice of a row.
    const int  srow   = tid >> 8;        // 0 or 1
    const int  scol   = tid & 255;       // float2 index within row
    const bool lvalid = (scol < STEP);   // 2*scol < 500
    const float* xc   = x + (size_t)g * STEP + 2 * scol;

    #pragma unroll
    for (int bb = 0; bb < 2; ++bb) {
        float2 v[8];
        #pragma unroll
        for (int j = 0; j < 8; ++j) {                // 8 loads in flight
            const int row = (bb * 8 + j) * 2 + srow;
            const int gr  = min(m0 + row, batch - 1);
            v[j] = lvalid ? *(const float2*)(xc + (size_t)gr * INPUT)
                          : float2{0.f, 0.f};
        }
        #pragma unroll
        for (int j = 0; j < 8; ++j) {
            const int row = (bb * 8 + j) * 2 + srow;
            *(unsigned*)&As[row * LDA + 2 * scol] = bf2pack(v[j].x, v[j].y);
        }
    }

    float4v acc = {0.f, 0.f, 0.f, 0.f};
    // B fragment base: Wb[g][nb+fm][l4*8 + kk*32], one 16-B L2-hit load per k-step
    const __hip_bfloat16* wp = Wb + ((size_t)g * OPG + nb + fm) * KP + l4 * 8;
    const int arow = mwave * 16 + fm;

    __syncthreads();                                 // the only barrier

    // ---- barrier-free K loop: 16 steps of 32, one MFMA per step per wave ----
    #pragma unroll
    for (int kk = 0; kk < 16; ++kk) {
        const short8 b = *(const short8*)(wp + kk * 32);
        const short8 a = *(const short8*)&As[arow * LDA + kk * 32 + l4 * 8];
        acc = __builtin_amdgcn_mfma_f32_16x16x32_bf16(a, b, acc, 0, 0, 0);
    }

    // ---- epilogue: C/D col=lane&15, row=(lane>>4)*4+reg; relu + store ----
    // n-wave 3 computes cols 34..49 but stores only 48,49 (n-waves 0-2 cover 0..47)
    if (nwave < 3 || fm >= 14) {
        const int col = g * OPG + nb + fm;
        #pragma unroll
        for (int reg = 0; reg < 4; ++reg) {
            const int row = m0 + mwave * 16 + l4 * 4 + reg;
            if (row < batch)
                out[(size_t)row * OUTW + col] = fmaxf(acc[reg], 0.f);
        }
    }
}

extern "C" void kernel_launch(void* const* d_in, const int* in_sizes, int n_in,
                              void* d_out, int out_size, void* d_ws, size_t ws_size,
                              hipStream_t stream) {
    const float* x = (const float*)d_in[0];   // (batch, 10000) fp32
    const float* W = (const float*)d_in[1];   // (39, 50, 500) fp32
    float* out     = (float*)d_out;           // (batch, 1950) fp32

    const int batch = in_sizes[0] / INPUT;    // 4096

    // prep: W fp32 -> Wb bf16 (K padded to 512, zeros beyond 500)
    const int slots = GROUPS * OPG * (KP / 2);            // 499,200
    prep_w<<<(slots + 255) / 256, 256, 0, stream>>>(W);

    dim3 grid(GROUPS, (batch + BM - 1) / BM);             // 39 x 128 = 4992
    peak_binner_kernel<<<grid, dim3(512), 0, stream>>>(x, out, batch);
}

// Round 2
// 275.445 us; speedup vs baseline: 1.0991x; 1.0991x over previous
//
#include <hip/hip_runtime.h>
#include <hip/hip_bf16.h>

// PeakBinner: out[b, g*50+o] = relu( sum_k x[b, g*250+k] * W[g,o,k] )
// Round 7: B register-resident. Same 256-thread / BM=32 / 33.3 KB LDS / one
// barrier skeleton as the 106us round-5 kernel, but the K-loop's 16 L2-hit
// B-loads are hoisted out of the loop: b_lo[8] prefetched BEFORE staging
// (L2 latency hides under the staging HBM wait), b_hi[8] issued right after
// the barrier (hides under part-1 MFMA+ds_read). K-loop is pure LDS+MFMA.
// Staging batched 16-deep (2 HBM waits instead of 4).
// __launch_bounds__(256,4) -> VGPR cap 128 (est. ~110 peak, no spill).

constexpr int INPUT  = 10000;
constexpr int GROUPS = 39;
constexpr int GS     = 500;
constexpr int STEP   = 250;
constexpr int OPG    = 50;
constexpr int OUTW   = 1950;
constexpr int KP     = 512;          // padded K
constexpr int BM     = 32;
constexpr int LDA    = KP + 8;       // shorts; 1040-B row stride (4 banks mod 32)

__device__ __hip_bfloat16 Wb[GROUPS * OPG * KP];   // 2.0 MB, L2-resident

typedef __attribute__((ext_vector_type(8))) short  short8;
typedef __attribute__((ext_vector_type(4))) float  float4v;

__device__ __forceinline__ unsigned bf2pack(float a, float b) {
    union { float f; unsigned u; } x, y; x.f = a; y.f = b;
    unsigned lo = (x.u + 0x7fffu + ((x.u >> 16) & 1u)) >> 16;
    unsigned hi = (y.u + 0x7fffu + ((y.u >> 16) & 1u)) & 0xffff0000u;
    return hi | lo;
}

__global__ void prep_w(const float* __restrict__ W) {
    const int slot = blockIdx.x * 256 + threadIdx.x;     // dword slots
    if (slot >= GROUPS * OPG * (KP / 2)) return;
    const int go = slot / (KP / 2);
    const int k  = (slot - go * (KP / 2)) * 2;
    float2 v = {0.f, 0.f};
    if (k < GS) v = *(const float2*)(W + (size_t)go * GS + k);
    ((unsigned*)Wb)[slot] = bf2pack(v.x, v.y);
}

__global__ __launch_bounds__(256, 4)
void peak_binner_kernel(const float* __restrict__ x,
                        float* __restrict__ out, int batch)
{
    __shared__ __align__(16) short As[BM * LDA];   // 33,280 B -> 4 blocks/CU

    const int g    = blockIdx.x;
    const int m0   = blockIdx.y * BM;
    const int tid  = threadIdx.x;
    const int lane = tid & 63;
    const int wave = tid >> 6;
    const int fm   = lane & 15;
    const int l4   = lane >> 4;
    const int nb   = (wave == 3) ? 34 : wave * 16;   // wave n-rows nb..nb+15

    // ---- prefetch low half of B fragments (kk 0..7) before staging ----
    // Wb[g][nb+fm][l4*8 + kk*32]; L2-hit latency hides under staging below.
    const __hip_bfloat16* wp = Wb + ((size_t)g * OPG + nb + fm) * KP + l4 * 8;
    short8 blo[8];
    #pragma unroll
    for (int j = 0; j < 8; ++j)
        blo[j] = *(const short8*)(wp + j * 32);

    // ---- stage A: 32 rows x 500 fp32 -> bf16, cols 500..511 zeroed ----
    // thread tid handles float2 at col 2*tid (tid>=250 stores zeros = pad);
    // 16 loads in flight per batch, 2 batches -> 2 HBM latency exposures.
    const bool lvalid = (tid < STEP);                // 2*tid < 500
    #pragma unroll
    for (int h = 0; h < 2; ++h) {
        float2 v[16];
        #pragma unroll
        for (int j = 0; j < 16; ++j) {
            const int it = h * 16 + j;
            const int gr = min(m0 + it, batch - 1);
            v[j] = lvalid ? *(const float2*)(x + (size_t)gr * INPUT + g * STEP + 2 * tid)
                          : float2{0.f, 0.f};
        }
        #pragma unroll
        for (int j = 0; j < 16; ++j) {
            const int it = h * 16 + j;
            *(unsigned*)&As[it * LDA + 2 * tid] = bf2pack(v[j].x, v[j].y);
        }
    }

    // keep blo live / issued on this side of the barrier
    #pragma unroll
    for (int j = 0; j < 8; ++j)
        asm volatile("" :: "v"(blo[j]));

    float4v acc[2] = {{0,0,0,0},{0,0,0,0}};

    __syncthreads();                                 // the only barrier

    // ---- issue high half of B (kk 8..15); latency hides under part 1 ----
    short8 bhi[8];
    #pragma unroll
    for (int j = 0; j < 8; ++j)
        bhi[j] = *(const short8*)(wp + (8 + j) * 32);

    // ---- barrier-free K loop: pure ds_read + MFMA ----
    #pragma unroll
    for (int kk = 0; kk < 8; ++kk) {
        const short8 a0 = *(const short8*)&As[fm        * LDA + kk * 32 + l4 * 8];
        const short8 a1 = *(const short8*)&As[(16 + fm) * LDA + kk * 32 + l4 * 8];
        acc[0] = __builtin_amdgcn_mfma_f32_16x16x32_bf16(a0, blo[kk], acc[0], 0, 0, 0);
        acc[1] = __builtin_amdgcn_mfma_f32_16x16x32_bf16(a1, blo[kk], acc[1], 0, 0, 0);
    }
    #pragma unroll
    for (int kk = 0; kk < 8; ++kk) {
        const short8 a0 = *(const short8*)&As[fm        * LDA + (8 + kk) * 32 + l4 * 8];
        const short8 a1 = *(const short8*)&As[(16 + fm) * LDA + (8 + kk) * 32 + l4 * 8];
        acc[0] = __builtin_amdgcn_mfma_f32_16x16x32_bf16(a0, bhi[kk], acc[0], 0, 0, 0);
        acc[1] = __builtin_amdgcn_mfma_f32_16x16x32_bf16(a1, bhi[kk], acc[1], 0, 0, 0);
    }

    // ---- epilogue: C/D col=lane&15, row=(lane>>4)*4+reg; relu + store ----
    // wave3 computes cols 34..49 but stores only 48,49 (waves 0-2 cover 0..47)
    if (wave < 3 || fm >= 14) {
        const int col = g * OPG + nb + fm;
        #pragma unroll
        for (int mt = 0; mt < 2; ++mt)
            #pragma unroll
            for (int reg = 0; reg < 4; ++reg) {
                const int row = m0 + mt * 16 + l4 * 4 + reg;
                if (row < batch)
                    out[(size_t)row * OUTW + col] = fmaxf(acc[mt][reg], 0.f);
            }
    }
}

extern "C" void kernel_launch(void* const* d_in, const int* in_sizes, int n_in,
                              void* d_out, int out_size, void* d_ws, size_t ws_size,
                              hipStream_t stream) {
    const float* x = (const float*)d_in[0];   // (batch, 10000) fp32
    const float* W = (const float*)d_in[1];   // (39, 50, 500) fp32
    float* out     = (float*)d_out;           // (batch, 1950) fp32

    const int batch = in_sizes[0] / INPUT;    // 4096

    // prep: W fp32 -> Wb bf16 (K padded to 512, zeros beyond 500)
    const int slots = GROUPS * OPG * (KP / 2);            // 499,200
    prep_w<<<(slots + 255) / 256, 256, 0, stream>>>(W);

    dim3 grid(GROUPS, (batch + BM - 1) / BM);             // 39 x 128 = 4992
    peak_binner_kernel<<<grid, dim3(256), 0, stream>>>(x, out, batch);
}